// Round 1
// baseline (240.903 us; speedup 1.0000x reference)
//
#include <hip/hip_runtime.h>
#include <math.h>

typedef __bf16 bf16x8 __attribute__((ext_vector_type(8)));
typedef float f32x4 __attribute__((ext_vector_type(4)));
typedef unsigned short ushort_t;

#define SEQ 2048
#define MROWS 4096          // B*S
#define EPS 1e-5f
#define QKS 3200            // fused qkv output row stride (q 0..1023, k 1024.., v 2048.., gate 3072..3087, pad)
#define LOG2E 1.4426950408889634f
#define SMAX_B2 17.32f      // static softmax max in base-2 units (= 12 * log2e; |s|<=8.1 by Cauchy-Schwarz)

#if __has_builtin(__builtin_amdgcn_exp2f)
#define EXP2(x) __builtin_amdgcn_exp2f(x)
#else
#define EXP2(x) exp2f(x)
#endif

// ---------- bf16 helpers ----------
__device__ __forceinline__ float bf2f(ushort_t u) {
  union { unsigned int i; float f; } c; c.i = ((unsigned int)u) << 16; return c.f;
}
__device__ __forceinline__ ushort_t f2bf(float f) {           // manual RNE (cold paths)
  union { unsigned int i; float f; } c; c.f = f;
  unsigned int i = c.i;
  unsigned int r = i + 0x7fffu + ((i >> 16) & 1u);
  return (ushort_t)(r >> 16);
}
__device__ __forceinline__ ushort_t f2bf_fast(float f) {      // native v_cvt (flash hot path)
  union { __bf16 b; ushort_t u; } cv; cv.b = (__bf16)f; return cv.u;
}

// ---------- reductions ----------
__device__ __forceinline__ float wave_sum(float v) {
  #pragma unroll
  for (int off = 32; off > 0; off >>= 1) v += __shfl_xor(v, off);
  return v;
}

// ---------- 0a. dtype detector: is x bf16 (1) or fp32 (0)? ----------
__global__ void detect_kernel(const unsigned int* __restrict__ xraw, int* __restrict__ flag) {
  int tid = threadIdx.x;
  int cnt = 0;
  for (int i = tid; i < 4096; i += 256) {
    unsigned int e = (xraw[i] >> 7) & 0xFFu;
    cnt += (e >= 100u && e <= 150u) ? 1 : 0;
  }
  __shared__ int sred[256];
  sred[tid] = cnt;
  __syncthreads();
  for (int s = 128; s > 0; s >>= 1) {
    if (tid < s) sred[tid] += sred[tid + s];
    __syncthreads();
  }
  if (tid == 0) flag[0] = (sred[0] > 2048) ? 1 : 0;
}

// ---------- 0b. single merged weight-prep kernel (replaces 6 conv launches) ----------
__global__ void prep_kernel(const void* __restrict__ qkvw_in, const void* __restrict__ gw_in,
                            const void* __restrict__ ow_in, const void* __restrict__ pw_in,
                            const void* __restrict__ qn_in, const void* __restrict__ kn_in,
                            ushort_t* __restrict__ Wcat, ushort_t* __restrict__ ow,
                            float* __restrict__ pwf, float* __restrict__ qnf,
                            float* __restrict__ knf, const int* __restrict__ flag) {
  int bid = blockIdx.x, tid = threadIdx.x;
  int bf = *flag;
  if (bid < 12288) {                      // qkv_w -> Wcat rows 0..3071
    int i = bid * 256 + tid;
    Wcat[i] = bf ? ((const ushort_t*)qkvw_in)[i] : f2bf(((const float*)qkvw_in)[i]);
  } else if (bid < 12352) {               // gate_w -> Wcat rows 3072..3087
    int i = (bid - 12288) * 256 + tid;
    Wcat[3072 * 1024 + i] = bf ? ((const ushort_t*)gw_in)[i] : f2bf(((const float*)gw_in)[i]);
  } else if (bid < 16448) {               // o_w
    int i = (bid - 12352) * 256 + tid;
    ow[i] = bf ? ((const ushort_t*)ow_in)[i] : f2bf(((const float*)ow_in)[i]);
  } else {                                // prenorm_w (1024 f32) + q/k norm weights (64 each)
    for (int i = tid; i < 1024; i += 256)
      pwf[i] = bf ? bf2f(((const ushort_t*)pw_in)[i]) : ((const float*)pw_in)[i];
    if (tid < 64) {
      qnf[tid] = bf ? bf2f(((const ushort_t*)qn_in)[tid]) : ((const float*)qn_in)[tid];
      knf[tid] = bf ? bf2f(((const ushort_t*)kn_in)[tid]) : ((const float*)kn_in)[tid];
    }
  }
}

// ---------- 1. prenorm RMSNorm (raw x per flag -> bf16 xn) ----------
__global__ void prenorm_kernel(const void* __restrict__ xraw,
                               const float* __restrict__ w,
                               ushort_t* __restrict__ xn,
                               const int* __restrict__ flag) {
  int row = blockIdx.x;
  int tid = threadIdx.x;
  float4 u;
  if (*flag) {
    ushort4 s = ((const ushort4*)xraw)[row * 256 + tid];
    u.x = bf2f(s.x); u.y = bf2f(s.y); u.z = bf2f(s.z); u.w = bf2f(s.w);
  } else {
    u = ((const float4*)xraw)[row * 256 + tid];
  }
  float ss = u.x*u.x + u.y*u.y + u.z*u.z + u.w*u.w;
  ss = wave_sum(ss);
  __shared__ float red[4];
  if ((tid & 63) == 0) red[tid >> 6] = ss;
  __syncthreads();
  float total = red[0] + red[1] + red[2] + red[3];
  float inv = rsqrtf(total * (1.0f / 1024.0f) + EPS);
  float4 wu = ((const float4*)w)[tid];
  ushort4 o;
  o.x = f2bf(u.x * inv * wu.x);
  o.y = f2bf(u.y * inv * wu.y);
  o.z = f2bf(u.z * inv * wu.z);
  o.w = f2bf(u.w * inv * wu.w);
  ((ushort4*)(xn + (long long)row * 1024))[tid] = o;
}

// ---------- async global->LDS 16B ----------
__device__ __forceinline__ void gll16(const ushort_t* g, ushort_t* l) {
  __builtin_amdgcn_global_load_lds(
      (const __attribute__((address_space(1))) unsigned int*)g,
      (__attribute__((address_space(3))) unsigned int*)l, 16, 0, 0);
}

// ---------- 2. fused qkv+gate GEMM, 128x128 tile (m97 structure) ----------
// q gets 0.125*log2e folded in (flash softmax runs base-2, static max).
__global__ void gemm_qkv_fused(const ushort_t* __restrict__ A, const ushort_t* __restrict__ B,
                               ushort_t* __restrict__ C, float* __restrict__ gate,
                               const float* __restrict__ qw, const float* __restrict__ kw) {
  __shared__ ushort_t As[128 * 32];
  __shared__ ushort_t Bs[128 * 32];
  int tid = threadIdx.x, wave = tid >> 6, lane = tid & 63;
  int m_blk = blockIdx.y * 128, n_blk = blockIdx.x * 128;
  int wm = (wave & 1) * 64, wn = (wave >> 1) * 64;
  int g = lane >> 4, c = lane & 15;
  int arow = lane >> 2;
  int akc = (lane & 3) << 3;
  f32x4 acc[4][4] = {};
  for (int kt = 0; kt < 1024; kt += 32) {
    #pragma unroll
    for (int i = 0; i < 2; ++i) {
      int rbase = (i * 4 + wave) * 16;
      gll16(A + (long long)(m_blk + rbase + arow) * 1024 + kt + akc, &As[rbase * 32]);
      gll16(B + (long long)(n_blk + rbase + arow) * 1024 + kt + akc, &Bs[rbase * 32]);
    }
    __syncthreads();
    bf16x8 af[4], bfr[4];
    #pragma unroll
    for (int mi = 0; mi < 4; ++mi)
      af[mi] = *(const bf16x8*)&As[(wm + mi * 16 + c) * 32 + (g << 3)];
    #pragma unroll
    for (int ni = 0; ni < 4; ++ni)
      bfr[ni] = *(const bf16x8*)&Bs[(wn + ni * 16 + c) * 32 + (g << 3)];
    #pragma unroll
    for (int mi = 0; mi < 4; ++mi)
      #pragma unroll
      for (int ni = 0; ni < 4; ++ni)
        acc[mi][ni] = __builtin_amdgcn_mfma_f32_16x16x32_bf16(af[mi], bfr[ni], acc[mi][ni], 0, 0, 0);
    __syncthreads();
  }
  int col_base = n_blk + wn;   // 64-aligned; never straddles q/k/v/gate boundaries
  if (col_base < 2048) {
    int isk = col_base >= 1024;
    float scale = isk ? 1.0f : (0.125f * LOG2E);   // softmax scale + base-2 fold on q
    const float* nw = isk ? kw : qw;
    float w[4];
    #pragma unroll
    for (int ni = 0; ni < 4; ++ni) w[ni] = nw[ni * 16 + c];
    #pragma unroll
    for (int mi = 0; mi < 4; ++mi)
      #pragma unroll
      for (int r = 0; r < 4; ++r) {
        float ss = 0.f;
        #pragma unroll
        for (int ni = 0; ni < 4; ++ni) ss += acc[mi][ni][r] * acc[mi][ni][r];
        #pragma unroll
        for (int off = 8; off > 0; off >>= 1) ss += __shfl_xor(ss, off);
        float inv = rsqrtf(ss * (1.0f / 64.0f) + EPS) * scale;
        int row = m_blk + wm + mi * 16 + g * 4 + r;
        #pragma unroll
        for (int ni = 0; ni < 4; ++ni)
          C[(long long)row * QKS + col_base + ni * 16 + c] = f2bf(acc[mi][ni][r] * inv * w[ni]);
      }
  } else if (col_base < 3072) {
    #pragma unroll
    for (int mi = 0; mi < 4; ++mi)
      #pragma unroll
      for (int r = 0; r < 4; ++r) {
        int row = m_blk + wm + mi * 16 + g * 4 + r;
        #pragma unroll
        for (int ni = 0; ni < 4; ++ni)
          C[(long long)row * QKS + col_base + ni * 16 + c] = f2bf(acc[mi][ni][r]);
      }
  } else if (col_base == 3072) {
    #pragma unroll
    for (int mi = 0; mi < 4; ++mi)
      #pragma unroll
      for (int r = 0; r < 4; ++r) {
        int row = m_blk + wm + mi * 16 + g * 4 + r;
        float v = acc[mi][0][r];
        gate[(long long)row * 16 + c] = 1.0f / (1.0f + __expf(-v));
      }
  }
}

// ---------- 3. generic tiled GEMM (o-proj): C=A@B^T (+res), dtype-dispatched ----------
__global__ void gemm_tiled(const ushort_t* __restrict__ A, const ushort_t* __restrict__ B,
                           void* __restrict__ Cv, const void* __restrict__ res,
                           const int* __restrict__ flag,
                           int K, int lda, int ldb, int ldc) {
  __shared__ ushort_t As[128 * 32];
  __shared__ ushort_t Bs[128 * 32];
  int tid = threadIdx.x, wave = tid >> 6, lane = tid & 63;
  int m_blk = blockIdx.y * 128, n_blk = blockIdx.x * 128;
  int wm = (wave & 1) * 64, wn = (wave >> 1) * 64;
  int g = lane >> 4, c = lane & 15;
  int arow = lane >> 2;
  int akc = (lane & 3) << 3;
  f32x4 acc[4][4] = {};
  for (int kt = 0; kt < K; kt += 32) {
    #pragma unroll
    for (int i = 0; i < 2; ++i) {
      int rbase = (i * 4 + wave) * 16;
      gll16(A + (long long)(m_blk + rbase + arow) * lda + kt + akc, &As[rbase * 32]);
      gll16(B + (long long)(n_blk + rbase + arow) * ldb + kt + akc, &Bs[rbase * 32]);
    }
    __syncthreads();
    bf16x8 af[4], bfr[4];
    #pragma unroll
    for (int mi = 0; mi < 4; ++mi)
      af[mi] = *(const bf16x8*)&As[(wm + mi * 16 + c) * 32 + (g << 3)];
    #pragma unroll
    for (int ni = 0; ni < 4; ++ni)
      bfr[ni] = *(const bf16x8*)&Bs[(wn + ni * 16 + c) * 32 + (g << 3)];
    #pragma unroll
    for (int mi = 0; mi < 4; ++mi)
      #pragma unroll
      for (int ni = 0; ni < 4; ++ni)
        acc[mi][ni] = __builtin_amdgcn_mfma_f32_16x16x32_bf16(af[mi], bfr[ni], acc[mi][ni], 0, 0, 0);
    __syncthreads();
  }
  int outbf = flag ? *flag : 1;
  #pragma unroll
  for (int mi = 0; mi < 4; ++mi)
    #pragma unroll
    for (int ni = 0; ni < 4; ++ni)
      #pragma unroll
      for (int r = 0; r < 4; ++r) {
        int row = m_blk + wm + mi * 16 + g * 4 + r;
        int col = n_blk + wn + ni * 16 + c;
        long long idx = (long long)row * ldc + col;
        float v = acc[mi][ni][r];
        if (res) v += outbf ? bf2f(((const ushort_t*)res)[idx]) : ((const float*)res)[idx];
        if (outbf) ((ushort_t*)Cv)[idx] = f2bf(v);
        else       ((float*)Cv)[idx] = v;
      }
}

// ---------- 4. V transpose (bf16): Vt[bh][d][s] = qkv2[b*S+s][2048+h*64+d] ----------
__global__ void vt_kernel(const ushort_t* __restrict__ qkv, ushort_t* __restrict__ Vt) {
  __shared__ ushort_t tile[64][65];
  int s0 = blockIdx.x * 64;
  int bh = blockIdx.y;
  int b = bh >> 4, h = bh & 15;
  const ushort_t* src = qkv + (long long)b * SEQ * QKS + 2048 + h * 64;
  int d = threadIdx.x & 63, srow = threadIdx.x >> 6;
  #pragma unroll
  for (int i = 0; i < 16; ++i) {
    int sl = i * 4 + srow;
    tile[sl][d] = src[(long long)(s0 + sl) * QKS + d];
  }
  __syncthreads();
  ushort_t* dst = Vt + (long long)bh * 64 * SEQ + s0;
  int sl2 = threadIdx.x & 63, drow = threadIdx.x >> 6;
  #pragma unroll
  for (int i = 0; i < 16; ++i) {
    int dd = i * 4 + drow;
    dst[(long long)dd * SEQ + sl2] = tile[sl2][dd];
  }
}

// ---------- 5. flash attention: double-buffered K/V staging (T3-minimal pipeline) ----------
// grid (SEQ/64, 32). Static-max base-2 softmax (|s|<=8.1 by Cauchy-Schwarz after RMSNorm).
// Pipeline: stage(t+1 -> buf^1) issued BEFORE compute(t from buf); single __syncthreads
// per tile (its implicit vmcnt(0) drain is exactly the cross-wave publish we need).
// This keeps next-tile global_load_lds in flight under QK^T/softmax/PV instead of
// serially exposing load latency per tile (old: stage -> sync -> compute -> sync).
__global__ void flash_kernel(const ushort_t* __restrict__ qkv, const ushort_t* __restrict__ Vt,
                             const float* __restrict__ gate, ushort_t* __restrict__ ao) {
  __shared__ ushort_t Ks[2][64 * 64];
  __shared__ ushort_t Vs[2][64 * 64];
  __shared__ ushort_t Ps[4][16 * 64];
  int tid = threadIdx.x, wave = tid >> 6, lane = tid & 63;
  int g = lane >> 4, c = lane & 15;
  int q0 = blockIdx.x * 64;
  int bh = blockIdx.y, b = bh >> 4, h = bh & 15;
  const ushort_t* qbase = qkv + (long long)b * SEQ * QKS + h * 64;
  const ushort_t* kbase = qbase + 1024;
  const ushort_t* vtbase = Vt + (long long)bh * 64 * SEQ;
  // q A-fragment: m=c, k=8g+j (and +32)
  int qrow = q0 + wave * 16 + c;
  bf16x8 qa0 = *(const bf16x8*)(qbase + (long long)qrow * QKS + (g << 3));
  bf16x8 qa1 = *(const bf16x8*)(qbase + (long long)qrow * QKS + 32 + (g << 3));
  f32x4 accO[4] = {};
  float l_p[4] = {0.f, 0.f, 0.f, 0.f};   // per-lane l partials (rows 4g+r, this lane's 4 cols)
  int srow = lane >> 3;           // 0..7 within this wave's 8-row stage chunk
  int schk = lane & 7;            // physical 16B chunk this lane fills

  // async stage tile starting at S0 into buffer BUF; physical slot (row, schk)
  // holds global chunk schk^(row&7)
  #define STAGE(BUF, S0) do {                                                        \
    _Pragma("unroll")                                                                \
    for (int t = 0; t < 2; ++t) {                                                    \
      int rb = t * 32 + wave * 8;                                                    \
      int row = rb + srow;                                                           \
      int gch = (schk ^ (row & 7)) << 3;                                             \
      gll16(kbase + (long long)((S0) + row) * QKS + gch, &Ks[BUF][rb * 64]);         \
      gll16(vtbase + (long long)row * SEQ + (S0) + gch, &Vs[BUF][rb * 64]);          \
    } } while (0)

  // compute one 64-wide KV tile from buffer BUF
  #define COMPUTE(BUF) do {                                                          \
    f32x4 sacc[4] = {};                                                              \
    __builtin_amdgcn_s_setprio(1);                                                   \
    _Pragma("unroll")                                                                \
    for (int ni = 0; ni < 4; ++ni) {                                                 \
      int n = ni * 16 + c;                                                           \
      bf16x8 kb0 = *(const bf16x8*)&Ks[BUF][n * 64 + ((g ^ (n & 7)) << 3)];          \
      bf16x8 kb1 = *(const bf16x8*)&Ks[BUF][n * 64 + (((4 + g) ^ (n & 7)) << 3)];    \
      sacc[ni] = __builtin_amdgcn_mfma_f32_16x16x32_bf16(qa0, kb0, sacc[ni], 0, 0, 0); \
      sacc[ni] = __builtin_amdgcn_mfma_f32_16x16x32_bf16(qa1, kb1, sacc[ni], 0, 0, 0); \
    }                                                                                \
    __builtin_amdgcn_s_setprio(0);                                                   \
    _Pragma("unroll")                                                                \
    for (int r = 0; r < 4; ++r) {                                                    \
      int q = g * 4 + r;                                                             \
      int sw = (q & 7) << 3;                                                         \
      _Pragma("unroll")                                                              \
      for (int ni = 0; ni < 4; ++ni) {                                               \
        float p = EXP2(sacc[ni][r] - SMAX_B2);                                       \
        l_p[r] += p;                                                                 \
        int col = ni * 16 + c;                                                       \
        Ps[wave][q * 64 + ((col & 56) ^ sw) + (col & 7)] = f2bf_fast(p);             \
      }                                                                              \
    }                                                                                \
    bf16x8 pa0 = *(const bf16x8*)&Ps[wave][c * 64 + ((g ^ (c & 7)) << 3)];           \
    bf16x8 pa1 = *(const bf16x8*)&Ps[wave][c * 64 + (((4 + g) ^ (c & 7)) << 3)];     \
    __builtin_amdgcn_s_setprio(1);                                                   \
    _Pragma("unroll")                                                                \
    for (int di = 0; di < 4; ++di) {                                                 \
      int n = di * 16 + c;                                                           \
      bf16x8 vb0 = *(const bf16x8*)&Vs[BUF][n * 64 + ((g ^ (n & 7)) << 3)];          \
      bf16x8 vb1 = *(const bf16x8*)&Vs[BUF][n * 64 + (((4 + g) ^ (n & 7)) << 3)];    \
      accO[di] = __builtin_amdgcn_mfma_f32_16x16x32_bf16(pa0, vb0, accO[di], 0, 0, 0); \
      accO[di] = __builtin_amdgcn_mfma_f32_16x16x32_bf16(pa1, vb1, accO[di], 0, 0, 0); \
    }                                                                                \
    __builtin_amdgcn_s_setprio(0);                                                   \
  } while (0)

  // prologue: fill buffer 0 with tile 0, publish
  STAGE(0, 0);
  __syncthreads();
  // main loop, 2 tiles per iteration (static buffer indices)
  for (int s0 = 0; s0 < SEQ; s0 += 128) {
    STAGE(1, s0 + 64);          // next tile in flight during compute
    COMPUTE(0);
    __syncthreads();            // drains this wave's stage loads + publishes buf1
    if (s0 + 128 < SEQ) STAGE(0, s0 + 128);
    COMPUTE(1);
    __syncthreads();
  }
  #undef STAGE
  #undef COMPUTE

  // epilogue: reduce l over the 16-lane c-group, then O * sigmoid(gate) / l
  #pragma unroll
  for (int r = 0; r < 4; ++r) {
    #pragma unroll
    for (int off = 8; off > 0; off >>= 1) l_p[r] += __shfl_xor(l_p[r], off);
    int row = q0 + wave * 16 + g * 4 + r;
    float sg = gate[(long long)(b * SEQ + row) * 16 + h];  // pre-sigmoided
    float scale = sg / l_p[r];
    #pragma unroll
    for (int di = 0; di < 4; ++di) {
      int col = h * 64 + di * 16 + c;
      ao[(long long)(b * SEQ + row) * 1024 + col] = f2bf_fast(accO[di][r] * scale);
    }
  }
}

extern "C" void kernel_launch(void* const* d_in, const int* in_sizes, int n_in,
                              void* d_out, int out_size, void* d_ws, size_t ws_size,
                              hipStream_t stream) {
  (void)in_sizes; (void)n_in; (void)out_size; (void)ws_size;
  char* ws = (char*)d_ws;
  ushort_t* Wcat = (ushort_t*)(ws);                             // 7 MB: 3200x1024 bf16 (qkvw|gw|pad)
  ushort_t* ow   = (ushort_t*)(ws + (7ll << 20));               // 2 MB bf16 1024x1024
  float*    pwf  = (float*)   (ws + (9ll << 20));               // 4 KB
  float*    qnf  = (float*)   (ws + (9ll << 20) + (8 << 10));
  float*    knf  = (float*)   (ws + (9ll << 20) + (12 << 10));
  int*      flag = (int*)     (ws + (9ll << 20) + (16 << 10));
  float*    gate = (float*)   (ws + (9ll << 20) + (64 << 10));  // 256 KB fp32 (sigmoided)
  ushort_t* xn   = (ushort_t*)(ws + (10ll << 20));              // 8 MB bf16 4096x1024
  ushort_t* qkv2 = (ushort_t*)(ws + (18ll << 20));              // 26 MB bf16 4096x3200
  ushort_t* Vt   = (ushort_t*)(ws + (44ll << 20));              // 8 MB bf16 32x64x2048
  ushort_t* ao   = (ushort_t*)(ws + (52ll << 20));              // 8 MB bf16 4096x1024

  // 0. detect + merged weight prep
  detect_kernel<<<1, 256, 0, stream>>>((const unsigned int*)d_in[0], flag);
  prep_kernel<<<16449, 256, 0, stream>>>(d_in[2], d_in[3], d_in[4], d_in[1], d_in[5], d_in[6],
                                         Wcat, ow, pwf, qnf, knf, flag);
  // 1. prenorm (raw x -> bf16 xn)
  prenorm_kernel<<<MROWS, 256, 0, stream>>>(d_in[0], pwf, xn, flag);
  // 2. fused qkv+gate GEMM with qk-norm / sigmoid epilogue (N=3200 incl. pad tile)
  gemm_qkv_fused<<<dim3(25, 32), 256, 0, stream>>>(xn, Wcat, qkv2, gate, qnf, knf);
  // 3. V transpose
  vt_kernel<<<dim3(32, 32), 256, 0, stream>>>(qkv2, Vt);
  // 4. flash attention (fused gate multiply, double-buffered pipeline)
  flash_kernel<<<dim3(32, 32), 256, 0, stream>>>(qkv2, Vt, gate, ao);
  // 5. out = ao @ o_w^T + x (raw residual), dtype-dispatched store
  gemm_tiled<<<dim3(8, 32), 256, 0, stream>>>(ao, ow, d_out, d_in[0], flag,
                                              1024, 1024, 1024, 1024);
}

// Round 3
// 233.924 us; speedup vs baseline: 1.0298x; 1.0298x over previous
//
#include <hip/hip_runtime.h>
#include <math.h>

typedef __bf16 bf16x8 __attribute__((ext_vector_type(8)));
typedef float f32x4 __attribute__((ext_vector_type(4)));
typedef float f32x16 __attribute__((ext_vector_type(16)));
typedef unsigned int uint2v __attribute__((ext_vector_type(2)));
typedef unsigned int uint4v __attribute__((ext_vector_type(4)));
typedef unsigned short ushort_t;

#define SEQ 2048
#define MROWS 4096          // B*S
#define EPS 1e-5f
#define QKS 3200            // fused qkv output row stride (q 0..1023, k 1024.., v 2048.., gate 3072..3087, pad)
#define LOG2E 1.4426950408889634f
#define SMAX_B2 17.32f      // static softmax max in base-2 units (= 12 * log2e; |s|<=8.1 by Cauchy-Schwarz)

#if __has_builtin(__builtin_amdgcn_exp2f)
#define EXP2(x) __builtin_amdgcn_exp2f(x)
#else
#define EXP2(x) exp2f(x)
#endif

// ---------- bf16 helpers ----------
__device__ __forceinline__ float bf2f(ushort_t u) {
  union { unsigned int i; float f; } c; c.i = ((unsigned int)u) << 16; return c.f;
}
__device__ __forceinline__ ushort_t f2bf(float f) {           // manual RNE (cold paths)
  union { unsigned int i; float f; } c; c.f = f;
  unsigned int i = c.i;
  unsigned int r = i + 0x7fffu + ((i >> 16) & 1u);
  return (ushort_t)(r >> 16);
}
__device__ __forceinline__ ushort_t f2bf_fast(float f) {      // native v_cvt (flash hot path)
  union { __bf16 b; ushort_t u; } cv; cv.b = (__bf16)f; return cv.u;
}

// pack 2 f32 -> 1 dword of 2 bf16 (lo=a, hi=b)
#define CVTPK(d, a, b) asm("v_cvt_pk_bf16_f32 %0, %1, %2" : "=v"(d) : "v"(a), "v"(b))

// exchange: a' = {lo: a@lo, hi: b@lo}; b' = {lo: a@hi, hi: b@hi}
__device__ __forceinline__ void plane_swap(unsigned int &a, unsigned int &b) {
#if __has_builtin(__builtin_amdgcn_permlane32_swap)
  uint2v r = __builtin_amdgcn_permlane32_swap(a, b, 0, 0);
  a = r.x; b = r.y;
#else
  unsigned int sa = (unsigned int)__shfl_xor((int)a, 32);
  unsigned int sb = (unsigned int)__shfl_xor((int)b, 32);
  int hi = (int)((threadIdx.x & 63) >> 5);
  unsigned int na = hi ? sb : a;
  unsigned int nb = hi ? b : sa;
  a = na; b = nb;
#endif
}

// softmax + pack for one 32-krow m-tile of S^T (32x32 C-layout):
// st reg r holds S^T[k=(r&3)+8*(r>>2)+4*hi][q=lane&31].
// Produces PV B-frags Fa (k 0..15 of this m-tile) and Fb (k 16..31):
// dword j = bf16 pair (k = base + hi*8 + 2j, +1) after permlane32_swap.
__device__ __forceinline__ void softmax_pack(const f32x16 &stv, float &lp,
                                             uint4v &Fa, uint4v &Fb) {
  float p[16];
  #pragma unroll
  for (int r = 0; r < 16; ++r) {
    p[r] = EXP2(stv[r] - SMAX_B2);
    lp += p[r];
  }
  unsigned int X00, X01, X10, X11, X20, X21, X30, X31;
  CVTPK(X00, p[0], p[1]);   CVTPK(X01, p[2], p[3]);    // quad t=0: krows 4*hi+{0..3}
  CVTPK(X10, p[4], p[5]);   CVTPK(X11, p[6], p[7]);    // t=1: 8+4*hi+{0..3}
  CVTPK(X20, p[8], p[9]);   CVTPK(X21, p[10], p[11]);  // t=2: 16+...
  CVTPK(X30, p[12], p[13]); CVTPK(X31, p[14], p[15]);  // t=3: 24+...
  plane_swap(X00, X10); plane_swap(X01, X11);
  plane_swap(X20, X30); plane_swap(X21, X31);
  Fa.x = X00; Fa.y = X01; Fa.z = X10; Fa.w = X11;
  Fb.x = X20; Fb.y = X21; Fb.z = X30; Fb.w = X31;
}

// ---------- reductions ----------
__device__ __forceinline__ float wave_sum(float v) {
  #pragma unroll
  for (int off = 32; off > 0; off >>= 1) v += __shfl_xor(v, off);
  return v;
}

// ---------- 0a. dtype detector: is x bf16 (1) or fp32 (0)? ----------
__global__ void detect_kernel(const unsigned int* __restrict__ xraw, int* __restrict__ flag) {
  int tid = threadIdx.x;
  int cnt = 0;
  for (int i = tid; i < 4096; i += 256) {
    unsigned int e = (xraw[i] >> 7) & 0xFFu;
    cnt += (e >= 100u && e <= 150u) ? 1 : 0;
  }
  __shared__ int sred[256];
  sred[tid] = cnt;
  __syncthreads();
  for (int s = 128; s > 0; s >>= 1) {
    if (tid < s) sred[tid] += sred[tid + s];
    __syncthreads();
  }
  if (tid == 0) flag[0] = (sred[0] > 2048) ? 1 : 0;
}

// ---------- 0b. single merged weight-prep kernel ----------
__global__ void prep_kernel(const void* __restrict__ qkvw_in, const void* __restrict__ gw_in,
                            const void* __restrict__ ow_in, const void* __restrict__ pw_in,
                            const void* __restrict__ qn_in, const void* __restrict__ kn_in,
                            ushort_t* __restrict__ Wcat, ushort_t* __restrict__ ow,
                            float* __restrict__ pwf, float* __restrict__ qnf,
                            float* __restrict__ knf, const int* __restrict__ flag) {
  int bid = blockIdx.x, tid = threadIdx.x;
  int bf = *flag;
  if (bid < 12288) {                      // qkv_w -> Wcat rows 0..3071
    int i = bid * 256 + tid;
    Wcat[i] = bf ? ((const ushort_t*)qkvw_in)[i] : f2bf(((const float*)qkvw_in)[i]);
  } else if (bid < 12352) {               // gate_w -> Wcat rows 3072..3087
    int i = (bid - 12288) * 256 + tid;
    Wcat[3072 * 1024 + i] = bf ? ((const ushort_t*)gw_in)[i] : f2bf(((const float*)gw_in)[i]);
  } else if (bid < 16448) {               // o_w
    int i = (bid - 12352) * 256 + tid;
    ow[i] = bf ? ((const ushort_t*)ow_in)[i] : f2bf(((const float*)ow_in)[i]);
  } else {                                // prenorm_w (1024 f32) + q/k norm weights (64 each)
    for (int i = tid; i < 1024; i += 256)
      pwf[i] = bf ? bf2f(((const ushort_t*)pw_in)[i]) : ((const float*)pw_in)[i];
    if (tid < 64) {
      qnf[tid] = bf ? bf2f(((const ushort_t*)qn_in)[tid]) : ((const float*)qn_in)[tid];
      knf[tid] = bf ? bf2f(((const ushort_t*)kn_in)[tid]) : ((const float*)kn_in)[tid];
    }
  }
}

// ---------- 1. prenorm RMSNorm (raw x per flag -> bf16 xn) ----------
__global__ void prenorm_kernel(const void* __restrict__ xraw,
                               const float* __restrict__ w,
                               ushort_t* __restrict__ xn,
                               const int* __restrict__ flag) {
  int row = blockIdx.x;
  int tid = threadIdx.x;
  float4 u;
  if (*flag) {
    ushort4 s = ((const ushort4*)xraw)[row * 256 + tid];
    u.x = bf2f(s.x); u.y = bf2f(s.y); u.z = bf2f(s.z); u.w = bf2f(s.w);
  } else {
    u = ((const float4*)xraw)[row * 256 + tid];
  }
  float ss = u.x*u.x + u.y*u.y + u.z*u.z + u.w*u.w;
  ss = wave_sum(ss);
  __shared__ float red[4];
  if ((tid & 63) == 0) red[tid >> 6] = ss;
  __syncthreads();
  float total = red[0] + red[1] + red[2] + red[3];
  float inv = rsqrtf(total * (1.0f / 1024.0f) + EPS);
  float4 wu = ((const float4*)w)[tid];
  ushort4 o;
  o.x = f2bf(u.x * inv * wu.x);
  o.y = f2bf(u.y * inv * wu.y);
  o.z = f2bf(u.z * inv * wu.z);
  o.w = f2bf(u.w * inv * wu.w);
  ((ushort4*)(xn + (long long)row * 1024))[tid] = o;
}

// ---------- async global->LDS 16B ----------
__device__ __forceinline__ void gll16(const ushort_t* g, ushort_t* l) {
  __builtin_amdgcn_global_load_lds(
      (const __attribute__((address_space(1))) unsigned int*)g,
      (__attribute__((address_space(3))) unsigned int*)l, 16, 0, 0);
}

// ---------- 2. fused qkv+gate GEMM, 128x128 tile (m97 structure) ----------
// q gets 0.125*log2e folded in (flash softmax runs base-2, static max).
__global__ void gemm_qkv_fused(const ushort_t* __restrict__ A, const ushort_t* __restrict__ B,
                               ushort_t* __restrict__ C, float* __restrict__ gate,
                               const float* __restrict__ qw, const float* __restrict__ kw) {
  __shared__ ushort_t As[128 * 32];
  __shared__ ushort_t Bs[128 * 32];
  int tid = threadIdx.x, wave = tid >> 6, lane = tid & 63;
  int m_blk = blockIdx.y * 128, n_blk = blockIdx.x * 128;
  int wm = (wave & 1) * 64, wn = (wave >> 1) * 64;
  int g = lane >> 4, c = lane & 15;
  int arow = lane >> 2;
  int akc = (lane & 3) << 3;
  f32x4 acc[4][4] = {};
  for (int kt = 0; kt < 1024; kt += 32) {
    #pragma unroll
    for (int i = 0; i < 2; ++i) {
      int rbase = (i * 4 + wave) * 16;
      gll16(A + (long long)(m_blk + rbase + arow) * 1024 + kt + akc, &As[rbase * 32]);
      gll16(B + (long long)(n_blk + rbase + arow) * 1024 + kt + akc, &Bs[rbase * 32]);
    }
    __syncthreads();
    bf16x8 af[4], bfr[4];
    #pragma unroll
    for (int mi = 0; mi < 4; ++mi)
      af[mi] = *(const bf16x8*)&As[(wm + mi * 16 + c) * 32 + (g << 3)];
    #pragma unroll
    for (int ni = 0; ni < 4; ++ni)
      bfr[ni] = *(const bf16x8*)&Bs[(wn + ni * 16 + c) * 32 + (g << 3)];
    #pragma unroll
    for (int mi = 0; mi < 4; ++mi)
      #pragma unroll
      for (int ni = 0; ni < 4; ++ni)
        acc[mi][ni] = __builtin_amdgcn_mfma_f32_16x16x32_bf16(af[mi], bfr[ni], acc[mi][ni], 0, 0, 0);
    __syncthreads();
  }
  int col_base = n_blk + wn;   // 64-aligned; never straddles q/k/v/gate boundaries
  if (col_base < 2048) {
    int isk = col_base >= 1024;
    float scale = isk ? 1.0f : (0.125f * LOG2E);   // softmax scale + base-2 fold on q
    const float* nw = isk ? kw : qw;
    float w[4];
    #pragma unroll
    for (int ni = 0; ni < 4; ++ni) w[ni] = nw[ni * 16 + c];
    #pragma unroll
    for (int mi = 0; mi < 4; ++mi)
      #pragma unroll
      for (int r = 0; r < 4; ++r) {
        float ss = 0.f;
        #pragma unroll
        for (int ni = 0; ni < 4; ++ni) ss += acc[mi][ni][r] * acc[mi][ni][r];
        #pragma unroll
        for (int off = 8; off > 0; off >>= 1) ss += __shfl_xor(ss, off);
        float inv = rsqrtf(ss * (1.0f / 64.0f) + EPS) * scale;
        int row = m_blk + wm + mi * 16 + g * 4 + r;
        #pragma unroll
        for (int ni = 0; ni < 4; ++ni)
          C[(long long)row * QKS + col_base + ni * 16 + c] = f2bf(acc[mi][ni][r] * inv * w[ni]);
      }
  } else if (col_base < 3072) {
    #pragma unroll
    for (int mi = 0; mi < 4; ++mi)
      #pragma unroll
      for (int r = 0; r < 4; ++r) {
        int row = m_blk + wm + mi * 16 + g * 4 + r;
        #pragma unroll
        for (int ni = 0; ni < 4; ++ni)
          C[(long long)row * QKS + col_base + ni * 16 + c] = f2bf(acc[mi][ni][r]);
      }
  } else if (col_base == 3072) {
    #pragma unroll
    for (int mi = 0; mi < 4; ++mi)
      #pragma unroll
      for (int r = 0; r < 4; ++r) {
        int row = m_blk + wm + mi * 16 + g * 4 + r;
        float v = acc[mi][0][r];
        gate[(long long)row * 16 + c] = 1.0f / (1.0f + __expf(-v));
      }
  }
}

// ---------- 3. generic tiled GEMM (o-proj): C=A@B^T (+res), dtype-dispatched ----------
__global__ void gemm_tiled(const ushort_t* __restrict__ A, const ushort_t* __restrict__ B,
                           void* __restrict__ Cv, const void* __restrict__ res,
                           const int* __restrict__ flag,
                           int K, int lda, int ldb, int ldc) {
  __shared__ ushort_t As[128 * 32];
  __shared__ ushort_t Bs[128 * 32];
  int tid = threadIdx.x, wave = tid >> 6, lane = tid & 63;
  int m_blk = blockIdx.y * 128, n_blk = blockIdx.x * 128;
  int wm = (wave & 1) * 64, wn = (wave >> 1) * 64;
  int g = lane >> 4, c = lane & 15;
  int arow = lane >> 2;
  int akc = (lane & 3) << 3;
  f32x4 acc[4][4] = {};
  for (int kt = 0; kt < K; kt += 32) {
    #pragma unroll
    for (int i = 0; i < 2; ++i) {
      int rbase = (i * 4 + wave) * 16;
      gll16(A + (long long)(m_blk + rbase + arow) * lda + kt + akc, &As[rbase * 32]);
      gll16(B + (long long)(n_blk + rbase + arow) * ldb + kt + akc, &Bs[rbase * 32]);
    }
    __syncthreads();
    bf16x8 af[4], bfr[4];
    #pragma unroll
    for (int mi = 0; mi < 4; ++mi)
      af[mi] = *(const bf16x8*)&As[(wm + mi * 16 + c) * 32 + (g << 3)];
    #pragma unroll
    for (int ni = 0; ni < 4; ++ni)
      bfr[ni] = *(const bf16x8*)&Bs[(wn + ni * 16 + c) * 32 + (g << 3)];
    #pragma unroll
    for (int mi = 0; mi < 4; ++mi)
      #pragma unroll
      for (int ni = 0; ni < 4; ++ni)
        acc[mi][ni] = __builtin_amdgcn_mfma_f32_16x16x32_bf16(af[mi], bfr[ni], acc[mi][ni], 0, 0, 0);
    __syncthreads();
  }
  int outbf = flag ? *flag : 1;
  #pragma unroll
  for (int mi = 0; mi < 4; ++mi)
    #pragma unroll
    for (int ni = 0; ni < 4; ++ni)
      #pragma unroll
      for (int r = 0; r < 4; ++r) {
        int row = m_blk + wm + mi * 16 + g * 4 + r;
        int col = n_blk + wn + ni * 16 + c;
        long long idx = (long long)row * ldc + col;
        float v = acc[mi][ni][r];
        if (res) v += outbf ? bf2f(((const ushort_t*)res)[idx]) : ((const float*)res)[idx];
        if (outbf) ((ushort_t*)Cv)[idx] = f2bf(v);
        else       ((float*)Cv)[idx] = v;
      }
}

// ---------- 4. V transpose (bf16): Vt[bh][d][s] = qkv2[b*S+s][2048+h*64+d] ----------
__global__ void vt_kernel(const ushort_t* __restrict__ qkv, ushort_t* __restrict__ Vt) {
  __shared__ ushort_t tile[64][65];
  int s0 = blockIdx.x * 64;
  int bh = blockIdx.y;
  int b = bh >> 4, h = bh & 15;
  const ushort_t* src = qkv + (long long)b * SEQ * QKS + 2048 + h * 64;
  int d = threadIdx.x & 63, srow = threadIdx.x >> 6;
  #pragma unroll
  for (int i = 0; i < 16; ++i) {
    int sl = i * 4 + srow;
    tile[sl][d] = src[(long long)(s0 + sl) * QKS + d];
  }
  __syncthreads();
  ushort_t* dst = Vt + (long long)bh * 64 * SEQ + s0;
  int sl2 = threadIdx.x & 63, drow = threadIdx.x >> 6;
  #pragma unroll
  for (int i = 0; i < 16; ++i) {
    int dd = i * 4 + drow;
    dst[(long long)dd * SEQ + sl2] = tile[sl2][dd];
  }
}

// ---------- 5. flash attention: 32x32 MFMA + swapped QK^T + in-register softmax (T12) ----------
// grid (SEQ/128, 32), 4 waves x 32 q-rows. KVBLK=64, double-buffered, no P LDS.
// S^T = mfma(K, Q^T): lane owns one q-col, 32 k-scores in regs (2 m-tiles x 16).
// P -> bf16 via v_cvt_pk_bf16_f32, PV B-frags assembled via permlane32_swap.
// O^T = mfma(Vt, P^T); l is a per-lane scalar, one shfl_xor(32) at the end.
// LDS traffic: 80 KB/tile/block for 128 q-rows (was 192 KB equiv) -> off the LDS-BW wall.
__global__ void flash_kernel(const ushort_t* __restrict__ qkv, const ushort_t* __restrict__ Vt,
                             const float* __restrict__ gate, ushort_t* __restrict__ ao) {
  __shared__ ushort_t Ks[2][64 * 64];
  __shared__ ushort_t Vs[2][64 * 64];
  int tid = threadIdx.x, wave = tid >> 6, lane = tid & 63;
  int al = lane & 31, hi = lane >> 5;
  int q0 = blockIdx.x * 128;
  int bh = blockIdx.y, b = bh >> 4, h = bh & 15;
  const ushort_t* qbase = qkv + (long long)b * SEQ * QKS + h * 64;
  const ushort_t* kbase = qbase + 1024;
  const ushort_t* vtbase = Vt + (long long)bh * 64 * SEQ;
  int qrow = q0 + wave * 32 + al;
  // Q B-frags: bq[dst] elem j = Q[qrow][dst*16 + hi*8 + j]  (B: col=lane&31, k=(lane>>5)*8+j)
  bf16x8 bq[4];
  #pragma unroll
  for (int dst = 0; dst < 4; ++dst)
    bq[dst] = *(const bf16x8*)(qbase + (long long)qrow * QKS + dst * 16 + hi * 8);
  f32x16 oac0 = {}, oac1 = {};
  float lp = 0.f;
  int srow = lane >> 3;           // 0..7 within this wave's 8-row stage chunk
  int schk = lane & 7;            // physical 16B chunk this lane fills

  // async stage tile starting at S0 into buffer BUF; physical slot (row, schk)
  // holds global chunk schk^(row&7)
  #define STAGE(BUF, S0) do {                                                        \
    _Pragma("unroll")                                                                \
    for (int t = 0; t < 2; ++t) {                                                    \
      int rb = t * 32 + wave * 8;                                                    \
      int row = rb + srow;                                                           \
      int gch = (schk ^ (row & 7)) << 3;                                             \
      gll16(kbase + (long long)((S0) + row) * QKS + gch, &Ks[BUF][rb * 64]);         \
      gll16(vtbase + (long long)row * SEQ + (S0) + gch, &Vs[BUF][rb * 64]);          \
    } } while (0)

  // compute one 64-wide KV tile from buffer BUF
  #define COMPUTE(BUF) do {                                                          \
    f32x16 st0 = {}, st1 = {};                                                       \
    __builtin_amdgcn_s_setprio(1);                                                   \
    _Pragma("unroll")                                                                \
    for (int dst = 0; dst < 4; ++dst) {                                              \
      int ph = (((dst << 1) | hi) ^ (al & 7)) << 3;                                  \
      bf16x8 ak0 = *(const bf16x8*)&Ks[BUF][al * 64 + ph];                           \
      bf16x8 ak1 = *(const bf16x8*)&Ks[BUF][(32 + al) * 64 + ph];                    \
      st0 = __builtin_amdgcn_mfma_f32_32x32x16_bf16(ak0, bq[dst], st0, 0, 0, 0);     \
      st1 = __builtin_amdgcn_mfma_f32_32x32x16_bf16(ak1, bq[dst], st1, 0, 0, 0);     \
    }                                                                                \
    __builtin_amdgcn_s_setprio(0);                                                   \
    uint4v Fa, Fb, Fc, Fd;                                                           \
    softmax_pack(st0, lp, Fa, Fb);                                                   \
    softmax_pack(st1, lp, Fc, Fd);                                                   \
    bf16x8 pf0 = __builtin_bit_cast(bf16x8, Fa);                                     \
    bf16x8 pf1 = __builtin_bit_cast(bf16x8, Fb);                                     \
    bf16x8 pf2 = __builtin_bit_cast(bf16x8, Fc);                                     \
    bf16x8 pf3 = __builtin_bit_cast(bf16x8, Fd);                                     \
    __builtin_amdgcn_s_setprio(1);                                                   \
    _Pragma("unroll")                                                                \
    for (int kst = 0; kst < 4; ++kst) {                                              \
      int ph = (((kst << 1) | hi) ^ (al & 7)) << 3;                                  \
      bf16x8 av0 = *(const bf16x8*)&Vs[BUF][al * 64 + ph];                           \
      bf16x8 av1 = *(const bf16x8*)&Vs[BUF][(32 + al) * 64 + ph];                    \
      bf16x8 pf = (kst == 0) ? pf0 : (kst == 1) ? pf1 : (kst == 2) ? pf2 : pf3;      \
      oac0 = __builtin_amdgcn_mfma_f32_32x32x16_bf16(av0, pf, oac0, 0, 0, 0);        \
      oac1 = __builtin_amdgcn_mfma_f32_32x32x16_bf16(av1, pf, oac1, 0, 0, 0);        \
    }                                                                                \
    __builtin_amdgcn_s_setprio(0);                                                   \
  } while (0)

  // prologue: fill buffer 0 with tile 0, publish
  STAGE(0, 0);
  __syncthreads();
  // main loop, 2 tiles per iteration (static buffer indices)
  for (int s0 = 0; s0 < SEQ; s0 += 128) {
    STAGE(1, s0 + 64);          // next tile in flight during compute
    COMPUTE(0);
    __syncthreads();            // drains this wave's stage loads + publishes buf1
    if (s0 + 128 < SEQ) STAGE(0, s0 + 128);
    COMPUTE(1);
    __syncthreads();
  }
  #undef STAGE
  #undef COMPUTE

  // epilogue: l = own 32-k partial + partner's; then O^T * sigmoid(gate) / l
  float ltot = lp + __shfl_xor(lp, 32);
  float sg = gate[(long long)(b * SEQ + qrow) * 16 + h];  // pre-sigmoided
  float scale = sg / ltot;
  ushort_t* aobase = ao + (long long)(b * SEQ + qrow) * 1024 + h * 64;
  // oacc reg r -> d = mt*32 + (r&3) + 8*(r>>2) + 4*hi
  #define OSTORE(OA, MT) do {                                                        \
    _Pragma("unroll")                                                                \
    for (int t = 0; t < 4; ++t) {                                                    \
      ushort4 o;                                                                     \
      o.x = f2bf_fast(OA[4 * t + 0] * scale);                                        \
      o.y = f2bf_fast(OA[4 * t + 1] * scale);                                        \
      o.z = f2bf_fast(OA[4 * t + 2] * scale);                                        \
      o.w = f2bf_fast(OA[4 * t + 3] * scale);                                        \
      *(ushort4*)(aobase + (MT) * 32 + 8 * t + 4 * hi) = o;                          \
    } } while (0)
  OSTORE(oac0, 0);
  OSTORE(oac1, 1);
  #undef OSTORE
}

extern "C" void kernel_launch(void* const* d_in, const int* in_sizes, int n_in,
                              void* d_out, int out_size, void* d_ws, size_t ws_size,
                              hipStream_t stream) {
  (void)in_sizes; (void)n_in; (void)out_size; (void)ws_size;
  char* ws = (char*)d_ws;
  ushort_t* Wcat = (ushort_t*)(ws);                             // 7 MB: 3200x1024 bf16 (qkvw|gw|pad)
  ushort_t* ow   = (ushort_t*)(ws + (7ll << 20));               // 2 MB bf16 1024x1024
  float*    pwf  = (float*)   (ws + (9ll << 20));               // 4 KB
  float*    qnf  = (float*)   (ws + (9ll << 20) + (8 << 10));
  float*    knf  = (float*)   (ws + (9ll << 20) + (12 << 10));
  int*      flag = (int*)     (ws + (9ll << 20) + (16 << 10));
  float*    gate = (float*)   (ws + (9ll << 20) + (64 << 10));  // 256 KB fp32 (sigmoided)
  ushort_t* xn   = (ushort_t*)(ws + (10ll << 20));              // 8 MB bf16 4096x1024
  ushort_t* qkv2 = (ushort_t*)(ws + (18ll << 20));              // 26 MB bf16 4096x3200
  ushort_t* Vt   = (ushort_t*)(ws + (44ll << 20));              // 8 MB bf16 32x64x2048
  ushort_t* ao   = (ushort_t*)(ws + (52ll << 20));              // 8 MB bf16 4096x1024

  // 0. detect + merged weight prep
  detect_kernel<<<1, 256, 0, stream>>>((const unsigned int*)d_in[0], flag);
  prep_kernel<<<16449, 256, 0, stream>>>(d_in[2], d_in[3], d_in[4], d_in[1], d_in[5], d_in[6],
                                         Wcat, ow, pwf, qnf, knf, flag);
  // 1. prenorm (raw x -> bf16 xn)
  prenorm_kernel<<<MROWS, 256, 0, stream>>>(d_in[0], pwf, xn, flag);
  // 2. fused qkv+gate GEMM with qk-norm / sigmoid epilogue (N=3200 incl. pad tile)
  gemm_qkv_fused<<<dim3(25, 32), 256, 0, stream>>>(xn, Wcat, qkv2, gate, qnf, knf);
  // 3. V transpose
  vt_kernel<<<dim3(32, 32), 256, 0, stream>>>(qkv2, Vt);
  // 4. flash attention (32x32 MFMA, in-register softmax, fused gate multiply)
  flash_kernel<<<dim3(16, 32), 256, 0, stream>>>(qkv2, Vt, gate, ao);
  // 5. out = ao @ o_w^T + x (raw residual), dtype-dispatched store
  gemm_tiled<<<dim3(8, 32), 256, 0, stream>>>(ao, ow, d_out, d_in[0], flag,
                                              1024, 1024, 1024, 1024);
}

// Round 5
// 230.384 us; speedup vs baseline: 1.0457x; 1.0154x over previous
//
#include <hip/hip_runtime.h>
#include <math.h>

typedef __bf16 bf16x8 __attribute__((ext_vector_type(8)));
typedef float f32x4 __attribute__((ext_vector_type(4)));
typedef float f32x16 __attribute__((ext_vector_type(16)));
typedef unsigned int uint2v __attribute__((ext_vector_type(2)));
typedef unsigned int uint4v __attribute__((ext_vector_type(4)));
typedef unsigned short ushort_t;

#define SEQ 2048
#define MROWS 4096          // B*S
#define EPS 1e-5f
#define QKS 3200            // fused qkv output row stride (q 0..1023, k 1024.., v 2048.., gate 3072..3087, pad)
#define LOG2E 1.4426950408889634f
#define SMAX_B2 17.32f      // static softmax max in base-2 units (= 12 * log2e; |s|<=8.1 by Cauchy-Schwarz)

// ---------- bf16 helpers ----------
__device__ __forceinline__ float bf2f(ushort_t u) {
  union { unsigned int i; float f; } c; c.i = ((unsigned int)u) << 16; return c.f;
}
__device__ __forceinline__ ushort_t f2bf(float f) {           // manual RNE (cold paths)
  union { unsigned int i; float f; } c; c.f = f;
  unsigned int i = c.i;
  unsigned int r = i + 0x7fffu + ((i >> 16) & 1u);
  return (ushort_t)(r >> 16);
}
__device__ __forceinline__ ushort_t f2bf_fast(float f) {      // native v_cvt (flash hot path)
  union { __bf16 b; ushort_t u; } cv; cv.b = (__bf16)f; return cv.u;
}

// raw 2^x — inputs are always in [-36, -3] here (no denormal/range concerns),
// so skip any libm wrapper and emit the bare trans-op.
__device__ __forceinline__ float exp2_raw(float x) {
  float r; asm("v_exp_f32 %0, %1" : "=v"(r) : "v"(x)); return r;
}

// pack 2 f32 -> 1 dword of 2 bf16 (lo=a, hi=b)
#define CVTPK(d, a, b) asm("v_cvt_pk_bf16_f32 %0, %1, %2" : "=v"(d) : "v"(a), "v"(b))

// exchange: a' = {lo: a@lo, hi: b@lo}; b' = {lo: a@hi, hi: b@hi}
__device__ __forceinline__ void plane_swap(unsigned int &a, unsigned int &b) {
#if __has_builtin(__builtin_amdgcn_permlane32_swap)
  uint2v r = __builtin_amdgcn_permlane32_swap(a, b, 0, 0);
  a = r.x; b = r.y;
#else
  unsigned int sa = (unsigned int)__shfl_xor((int)a, 32);
  unsigned int sb = (unsigned int)__shfl_xor((int)b, 32);
  int hi = (int)((threadIdx.x & 63) >> 5);
  unsigned int na = hi ? sb : a;
  unsigned int nb = hi ? b : sa;
  a = na; b = nb;
#endif
}

// softmax + pack for one 32-krow m-tile of S^T (32x32 C-layout):
// st reg r holds S^T[k=(r&3)+8*(r>>2)+4*hi][q=lane&31].
// Produces PV B-frags Fa (k 0..15 of this m-tile) and Fb (k 16..31):
// dword j = bf16 pair (k = base + hi*8 + 2j, +1) after permlane32_swap.
// l partial accumulated via depth-4 tree (not a 16-long serial chain).
__device__ __forceinline__ void softmax_pack(const f32x16 &stv, float &lp,
                                             uint4v &Fa, uint4v &Fb) {
  float p[16];
  #pragma unroll
  for (int r = 0; r < 16; ++r) p[r] = exp2_raw(stv[r] - SMAX_B2);
  float s0 = (p[0] + p[1]) + (p[2] + p[3]);
  float s1 = (p[4] + p[5]) + (p[6] + p[7]);
  float s2 = (p[8] + p[9]) + (p[10] + p[11]);
  float s3 = (p[12] + p[13]) + (p[14] + p[15]);
  lp += (s0 + s1) + (s2 + s3);
  unsigned int X00, X01, X10, X11, X20, X21, X30, X31;
  CVTPK(X00, p[0], p[1]);   CVTPK(X01, p[2], p[3]);    // quad t=0: krows 4*hi+{0..3}
  CVTPK(X10, p[4], p[5]);   CVTPK(X11, p[6], p[7]);    // t=1: 8+4*hi+{0..3}
  CVTPK(X20, p[8], p[9]);   CVTPK(X21, p[10], p[11]);  // t=2: 16+...
  CVTPK(X30, p[12], p[13]); CVTPK(X31, p[14], p[15]);  // t=3: 24+...
  plane_swap(X00, X10); plane_swap(X01, X11);
  plane_swap(X20, X30); plane_swap(X21, X31);
  Fa.x = X00; Fa.y = X01; Fa.z = X10; Fa.w = X11;
  Fb.x = X20; Fb.y = X21; Fb.z = X30; Fb.w = X31;
}

// ---------- reductions ----------
__device__ __forceinline__ float wave_sum(float v) {
  #pragma unroll
  for (int off = 32; off > 0; off >>= 1) v += __shfl_xor(v, off);
  return v;
}

// ---------- 0a. dtype detector: is x bf16 (1) or fp32 (0)? ----------
__global__ void detect_kernel(const unsigned int* __restrict__ xraw, int* __restrict__ flag) {
  int tid = threadIdx.x;
  int cnt = 0;
  for (int i = tid; i < 4096; i += 256) {
    unsigned int e = (xraw[i] >> 7) & 0xFFu;
    cnt += (e >= 100u && e <= 150u) ? 1 : 0;
  }
  __shared__ int sred[256];
  sred[tid] = cnt;
  __syncthreads();
  for (int s = 128; s > 0; s >>= 1) {
    if (tid < s) sred[tid] += sred[tid + s];
    __syncthreads();
  }
  if (tid == 0) flag[0] = (sred[0] > 2048) ? 1 : 0;
}

// ---------- 0b. single merged weight-prep kernel ----------
__global__ void prep_kernel(const void* __restrict__ qkvw_in, const void* __restrict__ gw_in,
                            const void* __restrict__ ow_in, const void* __restrict__ pw_in,
                            const void* __restrict__ qn_in, const void* __restrict__ kn_in,
                            ushort_t* __restrict__ Wcat, ushort_t* __restrict__ ow,
                            float* __restrict__ pwf, float* __restrict__ qnf,
                            float* __restrict__ knf, const int* __restrict__ flag) {
  int bid = blockIdx.x, tid = threadIdx.x;
  int bf = *flag;
  if (bid < 12288) {                      // qkv_w -> Wcat rows 0..3071
    int i = bid * 256 + tid;
    Wcat[i] = bf ? ((const ushort_t*)qkvw_in)[i] : f2bf(((const float*)qkvw_in)[i]);
  } else if (bid < 12352) {               // gate_w -> Wcat rows 3072..3087
    int i = (bid - 12288) * 256 + tid;
    Wcat[3072 * 1024 + i] = bf ? ((const ushort_t*)gw_in)[i] : f2bf(((const float*)gw_in)[i]);
  } else if (bid < 16448) {               // o_w
    int i = (bid - 12352) * 256 + tid;
    ow[i] = bf ? ((const ushort_t*)ow_in)[i] : f2bf(((const float*)ow_in)[i]);
  } else {                                // prenorm_w (1024 f32) + q/k norm weights (64 each)
    for (int i = tid; i < 1024; i += 256)
      pwf[i] = bf ? bf2f(((const ushort_t*)pw_in)[i]) : ((const float*)pw_in)[i];
    if (tid < 64) {
      qnf[tid] = bf ? bf2f(((const ushort_t*)qn_in)[tid]) : ((const float*)qn_in)[tid];
      knf[tid] = bf ? bf2f(((const ushort_t*)kn_in)[tid]) : ((const float*)kn_in)[tid];
    }
  }
}

// ---------- 1. prenorm RMSNorm (raw x per flag -> bf16 xn) ----------
__global__ void prenorm_kernel(const void* __restrict__ xraw,
                               const float* __restrict__ w,
                               ushort_t* __restrict__ xn,
                               const int* __restrict__ flag) {
  int row = blockIdx.x;
  int tid = threadIdx.x;
  float4 u;
  if (*flag) {
    ushort4 s = ((const ushort4*)xraw)[row * 256 + tid];
    u.x = bf2f(s.x); u.y = bf2f(s.y); u.z = bf2f(s.z); u.w = bf2f(s.w);
  } else {
    u = ((const float4*)xraw)[row * 256 + tid];
  }
  float ss = u.x*u.x + u.y*u.y + u.z*u.z + u.w*u.w;
  ss = wave_sum(ss);
  __shared__ float red[4];
  if ((tid & 63) == 0) red[tid >> 6] = ss;
  __syncthreads();
  float total = red[0] + red[1] + red[2] + red[3];
  float inv = rsqrtf(total * (1.0f / 1024.0f) + EPS);
  float4 wu = ((const float4*)w)[tid];
  ushort4 o;
  o.x = f2bf(u.x * inv * wu.x);
  o.y = f2bf(u.y * inv * wu.y);
  o.z = f2bf(u.z * inv * wu.z);
  o.w = f2bf(u.w * inv * wu.w);
  ((ushort4*)(xn + (long long)row * 1024))[tid] = o;
}

// ---------- async global->LDS 16B ----------
__device__ __forceinline__ void gll16(const ushort_t* g, ushort_t* l) {
  __builtin_amdgcn_global_load_lds(
      (const __attribute__((address_space(1))) unsigned int*)g,
      (__attribute__((address_space(3))) unsigned int*)l, 16, 0, 0);
}

// ---------- 2. fused qkv+gate GEMM, 128x128 tile (m97 structure) ----------
// q gets 0.125*log2e folded in (flash softmax runs base-2, static max).
__global__ void gemm_qkv_fused(const ushort_t* __restrict__ A, const ushort_t* __restrict__ B,
                               ushort_t* __restrict__ C, float* __restrict__ gate,
                               const float* __restrict__ qw, const float* __restrict__ kw) {
  __shared__ ushort_t As[128 * 32];
  __shared__ ushort_t Bs[128 * 32];
  int tid = threadIdx.x, wave = tid >> 6, lane = tid & 63;
  int m_blk = blockIdx.y * 128, n_blk = blockIdx.x * 128;
  int wm = (wave & 1) * 64, wn = (wave >> 1) * 64;
  int g = lane >> 4, c = lane & 15;
  int arow = lane >> 2;
  int akc = (lane & 3) << 3;
  f32x4 acc[4][4] = {};
  for (int kt = 0; kt < 1024; kt += 32) {
    #pragma unroll
    for (int i = 0; i < 2; ++i) {
      int rbase = (i * 4 + wave) * 16;
      gll16(A + (long long)(m_blk + rbase + arow) * 1024 + kt + akc, &As[rbase * 32]);
      gll16(B + (long long)(n_blk + rbase + arow) * 1024 + kt + akc, &Bs[rbase * 32]);
    }
    __syncthreads();
    bf16x8 af[4], bfr[4];
    #pragma unroll
    for (int mi = 0; mi < 4; ++mi)
      af[mi] = *(const bf16x8*)&As[(wm + mi * 16 + c) * 32 + (g << 3)];
    #pragma unroll
    for (int ni = 0; ni < 4; ++ni)
      bfr[ni] = *(const bf16x8*)&Bs[(wn + ni * 16 + c) * 32 + (g << 3)];
    #pragma unroll
    for (int mi = 0; mi < 4; ++mi)
      #pragma unroll
      for (int ni = 0; ni < 4; ++ni)
        acc[mi][ni] = __builtin_amdgcn_mfma_f32_16x16x32_bf16(af[mi], bfr[ni], acc[mi][ni], 0, 0, 0);
    __syncthreads();
  }
  int col_base = n_blk + wn;   // 64-aligned; never straddles q/k/v/gate boundaries
  if (col_base < 2048) {
    int isk = col_base >= 1024;
    float scale = isk ? 1.0f : (0.125f * LOG2E);   // softmax scale + base-2 fold on q
    const float* nw = isk ? kw : qw;
    float w[4];
    #pragma unroll
    for (int ni = 0; ni < 4; ++ni) w[ni] = nw[ni * 16 + c];
    #pragma unroll
    for (int mi = 0; mi < 4; ++mi)
      #pragma unroll
      for (int r = 0; r < 4; ++r) {
        float ss = 0.f;
        #pragma unroll
        for (int ni = 0; ni < 4; ++ni) ss += acc[mi][ni][r] * acc[mi][ni][r];
        #pragma unroll
        for (int off = 8; off > 0; off >>= 1) ss += __shfl_xor(ss, off);
        float inv = rsqrtf(ss * (1.0f / 64.0f) + EPS) * scale;
        int row = m_blk + wm + mi * 16 + g * 4 + r;
        #pragma unroll
        for (int ni = 0; ni < 4; ++ni)
          C[(long long)row * QKS + col_base + ni * 16 + c] = f2bf(acc[mi][ni][r] * inv * w[ni]);
      }
  } else if (col_base < 3072) {
    #pragma unroll
    for (int mi = 0; mi < 4; ++mi)
      #pragma unroll
      for (int r = 0; r < 4; ++r) {
        int row = m_blk + wm + mi * 16 + g * 4 + r;
        #pragma unroll
        for (int ni = 0; ni < 4; ++ni)
          C[(long long)row * QKS + col_base + ni * 16 + c] = f2bf(acc[mi][ni][r]);
      }
  } else if (col_base == 3072) {
    #pragma unroll
    for (int mi = 0; mi < 4; ++mi)
      #pragma unroll
      for (int r = 0; r < 4; ++r) {
        int row = m_blk + wm + mi * 16 + g * 4 + r;
        float v = acc[mi][0][r];
        gate[(long long)row * 16 + c] = 1.0f / (1.0f + __expf(-v));
      }
  }
}

// ---------- 3. generic tiled GEMM (o-proj): C=A@B^T (+res), dtype-dispatched ----------
__global__ void gemm_tiled(const ushort_t* __restrict__ A, const ushort_t* __restrict__ B,
                           void* __restrict__ Cv, const void* __restrict__ res,
                           const int* __restrict__ flag,
                           int K, int lda, int ldb, int ldc) {
  __shared__ ushort_t As[128 * 32];
  __shared__ ushort_t Bs[128 * 32];
  int tid = threadIdx.x, wave = tid >> 6, lane = tid & 63;
  int m_blk = blockIdx.y * 128, n_blk = blockIdx.x * 128;
  int wm = (wave & 1) * 64, wn = (wave >> 1) * 64;
  int g = lane >> 4, c = lane & 15;
  int arow = lane >> 2;
  int akc = (lane & 3) << 3;
  f32x4 acc[4][4] = {};
  for (int kt = 0; kt < K; kt += 32) {
    #pragma unroll
    for (int i = 0; i < 2; ++i) {
      int rbase = (i * 4 + wave) * 16;
      gll16(A + (long long)(m_blk + rbase + arow) * lda + kt + akc, &As[rbase * 32]);
      gll16(B + (long long)(n_blk + rbase + arow) * ldb + kt + akc, &Bs[rbase * 32]);
    }
    __syncthreads();
    bf16x8 af[4], bfr[4];
    #pragma unroll
    for (int mi = 0; mi < 4; ++mi)
      af[mi] = *(const bf16x8*)&As[(wm + mi * 16 + c) * 32 + (g << 3)];
    #pragma unroll
    for (int ni = 0; ni < 4; ++ni)
      bfr[ni] = *(const bf16x8*)&Bs[(wn + ni * 16 + c) * 32 + (g << 3)];
    #pragma unroll
    for (int mi = 0; mi < 4; ++mi)
      #pragma unroll
      for (int ni = 0; ni < 4; ++ni)
        acc[mi][ni] = __builtin_amdgcn_mfma_f32_16x16x32_bf16(af[mi], bfr[ni], acc[mi][ni], 0, 0, 0);
    __syncthreads();
  }
  int outbf = flag ? *flag : 1;
  #pragma unroll
  for (int mi = 0; mi < 4; ++mi)
    #pragma unroll
    for (int ni = 0; ni < 4; ++ni)
      #pragma unroll
      for (int r = 0; r < 4; ++r) {
        int row = m_blk + wm + mi * 16 + g * 4 + r;
        int col = n_blk + wn + ni * 16 + c;
        long long idx = (long long)row * ldc + col;
        float v = acc[mi][ni][r];
        if (res) v += outbf ? bf2f(((const ushort_t*)res)[idx]) : ((const float*)res)[idx];
        if (outbf) ((ushort_t*)Cv)[idx] = f2bf(v);
        else       ((float*)Cv)[idx] = v;
      }
}

// ---------- 4. V transpose (bf16): Vt[bh][d][s] = qkv2[b*S+s][2048+h*64+d] ----------
__global__ void vt_kernel(const ushort_t* __restrict__ qkv, ushort_t* __restrict__ Vt) {
  __shared__ ushort_t tile[64][65];
  int s0 = blockIdx.x * 64;
  int bh = blockIdx.y;
  int b = bh >> 4, h = bh & 15;
  const ushort_t* src = qkv + (long long)b * SEQ * QKS + 2048 + h * 64;
  int d = threadIdx.x & 63, srow = threadIdx.x >> 6;
  #pragma unroll
  for (int i = 0; i < 16; ++i) {
    int sl = i * 4 + srow;
    tile[sl][d] = src[(long long)(s0 + sl) * QKS + d];
  }
  __syncthreads();
  ushort_t* dst = Vt + (long long)bh * 64 * SEQ + s0;
  int sl2 = threadIdx.x & 63, drow = threadIdx.x >> 6;
  #pragma unroll
  for (int i = 0; i < 16; ++i) {
    int dd = i * 4 + drow;
    dst[(long long)dd * SEQ + sl2] = tile[sl2][dd];
  }
}

// ---------- 5. flash attention: 32x32 MFMA, in-reg softmax, depth-2 counted-vmcnt pipe ----------
// grid (SEQ/128, 32), 4 waves x 32 q-rows. KVBLK=64, 4 K-buffers + 4 V-buffers (64 KB).
// Swizzle f(r) = (r&7) ^ ((r>>3)&3): spreads the wave's 64 concurrent A-frag reads over
// all 8 16B-chunk columns for any stride-1/2/4/8 lane grouping (fixes the 4-way conflict
// measured with f(r)=r&7: 4.19M conflict-cycles/dispatch, exactly 4/read).
// Pipeline: STAGE(it+2); vmcnt(8) [retires tile it only]; s_barrier; COMPUTE(it).
// Next-tile loads stay in flight across the barrier (T4 counted-vmcnt); tail peeled
// with vmcnt(4)/vmcnt(0). Buffer (it+2)&3 was last read at it-2, separated by barriers.
// NOTE: macro-internal loop vars are named tt — round-4's NaN was the outer loop var `t`
// being captured by STAGE's internal `for (int t...)` (staged tiles 2,3 forever + race).
__global__ void flash_kernel(const ushort_t* __restrict__ qkv, const ushort_t* __restrict__ Vt,
                             const float* __restrict__ gate, ushort_t* __restrict__ ao) {
  __shared__ ushort_t Ks[4][64 * 64];
  __shared__ ushort_t Vs[4][64 * 64];
  int tid = threadIdx.x, wave = tid >> 6, lane = tid & 63;
  int al = lane & 31, hi = lane >> 5;
  int fal = (al & 7) ^ ((al >> 3) & 3);      // read-side swizzle term (f(al) == f(32+al))
  int q0 = blockIdx.x * 128;
  int bh = blockIdx.y, b = bh >> 4, h = bh & 15;
  const ushort_t* qbase = qkv + (long long)b * SEQ * QKS + h * 64;
  const ushort_t* kbase = qbase + 1024;
  const ushort_t* vtbase = Vt + (long long)bh * 64 * SEQ;
  int qrow = q0 + wave * 32 + al;
  // Q B-frags: bq[dst] elem j = Q[qrow][dst*16 + hi*8 + j]  (B: col=lane&31, k=(lane>>5)*8+j)
  bf16x8 bq[4];
  #pragma unroll
  for (int dst = 0; dst < 4; ++dst)
    bq[dst] = *(const bf16x8*)(qbase + (long long)qrow * QKS + dst * 16 + hi * 8);
  f32x16 oac0 = {}, oac1 = {};
  float lp = 0.f;
  int srow = lane >> 3;           // 0..7 within this wave's 8-row stage chunk
  int schk = lane & 7;            // physical 16B chunk this lane fills

  // stage tile at S0 into buffer BUF: phys chunk schk of row r holds global chunk
  // schk ^ f(r); f(r) = (r&7)^((r>>3)&3) = srow ^ wave here (r = tt*32 + wave*8 + srow).
  #define STAGE(BUF, S0) do {                                                        \
    int gch = ((schk ^ srow ^ wave) & 7) << 3;                                       \
    _Pragma("unroll")                                                                \
    for (int tt = 0; tt < 2; ++tt) {                                                 \
      int rb = tt * 32 + wave * 8;                                                   \
      int row = rb + srow;                                                           \
      gll16(kbase + (long long)((S0) + row) * QKS + gch, &Ks[BUF][rb * 64]);         \
      gll16(vtbase + (long long)row * SEQ + (S0) + gch, &Vs[BUF][rb * 64]);          \
    } } while (0)

  // counted-vmcnt barrier: retire my loads older than N, then block-sync.
  #define PIPE_BAR(N) do {                                                           \
    asm volatile("s_waitcnt vmcnt(" #N ")" ::: "memory");                            \
    __builtin_amdgcn_s_barrier();                                                    \
    asm volatile("" ::: "memory");                                                   \
  } while (0)

  // compute one 64-wide KV tile from buffer BUF
  #define COMPUTE(BUF) do {                                                          \
    f32x16 st0 = {}, st1 = {};                                                       \
    __builtin_amdgcn_s_setprio(1);                                                   \
    _Pragma("unroll")                                                                \
    for (int dst = 0; dst < 4; ++dst) {                                              \
      int ph = (((dst << 1) | hi) ^ fal) << 3;                                       \
      bf16x8 ak0 = *(const bf16x8*)&Ks[BUF][al * 64 + ph];                           \
      bf16x8 ak1 = *(const bf16x8*)&Ks[BUF][(32 + al) * 64 + ph];                    \
      st0 = __builtin_amdgcn_mfma_f32_32x32x16_bf16(ak0, bq[dst], st0, 0, 0, 0);     \
      st1 = __builtin_amdgcn_mfma_f32_32x32x16_bf16(ak1, bq[dst], st1, 0, 0, 0);     \
    }                                                                                \
    __builtin_amdgcn_s_setprio(0);                                                   \
    uint4v Fa, Fb, Fc, Fd;                                                           \
    softmax_pack(st0, lp, Fa, Fb);                                                   \
    softmax_pack(st1, lp, Fc, Fd);                                                   \
    bf16x8 pf0 = __builtin_bit_cast(bf16x8, Fa);                                     \
    bf16x8 pf1 = __builtin_bit_cast(bf16x8, Fb);                                     \
    bf16x8 pf2 = __builtin_bit_cast(bf16x8, Fc);                                     \
    bf16x8 pf3 = __builtin_bit_cast(bf16x8, Fd);                                     \
    __builtin_amdgcn_s_setprio(1);                                                   \
    _Pragma("unroll")                                                                \
    for (int kst = 0; kst < 4; ++kst) {                                              \
      int ph = (((kst << 1) | hi) ^ fal) << 3;                                       \
      bf16x8 av0 = *(const bf16x8*)&Vs[BUF][al * 64 + ph];                           \
      bf16x8 av1 = *(const bf16x8*)&Vs[BUF][(32 + al) * 64 + ph];                    \
      bf16x8 pf = (kst == 0) ? pf0 : (kst == 1) ? pf1 : (kst == 2) ? pf2 : pf3;      \
      oac0 = __builtin_amdgcn_mfma_f32_32x32x16_bf16(av0, pf, oac0, 0, 0, 0);        \
      oac1 = __builtin_amdgcn_mfma_f32_32x32x16_bf16(av1, pf, oac1, 0, 0, 0);        \
    }                                                                                \
    __builtin_amdgcn_s_setprio(0);                                                   \
  } while (0)

  // prologue: two tiles in flight
  STAGE(0, 0);
  STAGE(1, 64);
  // main loop: tiles 0..29, depth-2 prefetch, one barrier per tile, vmcnt never 0
  for (int it = 0; it < 30; ++it) {
    STAGE((it + 2) & 3, (it + 2) * 64);  // 4 loads; buffer last read at it-2 (barrier-separated)
    PIPE_BAR(8);                         // retires tile it's 4 loads; it+1/it+2 stay in flight
    COMPUTE(it & 3);
  }
  // tail: tile 30 (outstanding: 30's 4 + 31's 4)
  PIPE_BAR(4);
  COMPUTE(2);                            // 30 & 3
  // tail: tile 31
  PIPE_BAR(0);
  COMPUTE(3);                            // 31 & 3
  #undef STAGE
  #undef PIPE_BAR
  #undef COMPUTE

  // epilogue: l = own 32-k partial + partner's; then O^T * sigmoid(gate) / l
  float ltot = lp + __shfl_xor(lp, 32);
  float sg = gate[(long long)(b * SEQ + qrow) * 16 + h];  // pre-sigmoided
  float scale = sg / ltot;
  ushort_t* aobase = ao + (long long)(b * SEQ + qrow) * 1024 + h * 64;
  // oacc reg r -> d = mt*32 + (r&3) + 8*(r>>2) + 4*hi
  #define OSTORE(OA, MT) do {                                                        \
    _Pragma("unroll")                                                                \
    for (int tt = 0; tt < 4; ++tt) {                                                 \
      ushort4 o;                                                                     \
      o.x = f2bf_fast(OA[4 * tt + 0] * scale);                                       \
      o.y = f2bf_fast(OA[4 * tt + 1] * scale);                                       \
      o.z = f2bf_fast(OA[4 * tt + 2] * scale);                                       \
      o.w = f2bf_fast(OA[4 * tt + 3] * scale);                                       \
      *(ushort4*)(aobase + (MT) * 32 + 8 * tt + 4 * hi) = o;                         \
    } } while (0)
  OSTORE(oac0, 0);
  OSTORE(oac1, 1);
  #undef OSTORE
}

extern "C" void kernel_launch(void* const* d_in, const int* in_sizes, int n_in,
                              void* d_out, int out_size, void* d_ws, size_t ws_size,
                              hipStream_t stream) {
  (void)in_sizes; (void)n_in; (void)out_size; (void)ws_size;
  char* ws = (char*)d_ws;
  ushort_t* Wcat = (ushort_t*)(ws);                             // 7 MB: 3200x1024 bf16 (qkvw|gw|pad)
  ushort_t* ow   = (ushort_t*)(ws + (7ll << 20));               // 2 MB bf16 1024x1024
  float*    pwf  = (float*)   (ws + (9ll << 20));               // 4 KB
  float*    qnf  = (float*)   (ws + (9ll << 20) + (8 << 10));
  float*    knf  = (float*)   (ws + (9ll << 20) + (12 << 10));
  int*      flag = (int*)     (ws + (9ll << 20) + (16 << 10));
  float*    gate = (float*)   (ws + (9ll << 20) + (64 << 10));  // 256 KB fp32 (sigmoided)
  ushort_t* xn   = (ushort_t*)(ws + (10ll << 20));              // 8 MB bf16 4096x1024
  ushort_t* qkv2 = (ushort_t*)(ws + (18ll << 20));              // 26 MB bf16 4096x3200
  ushort_t* Vt   = (ushort_t*)(ws + (44ll << 20));              // 8 MB bf16 32x64x2048
  ushort_t* ao   = (ushort_t*)(ws + (52ll << 20));              // 8 MB bf16 4096x1024

  // 0. detect + merged weight prep
  detect_kernel<<<1, 256, 0, stream>>>((const unsigned int*)d_in[0], flag);
  prep_kernel<<<16449, 256, 0, stream>>>(d_in[2], d_in[3], d_in[4], d_in[1], d_in[5], d_in[6],
                                         Wcat, ow, pwf, qnf, knf, flag);
  // 1. prenorm (raw x -> bf16 xn)
  prenorm_kernel<<<MROWS, 256, 0, stream>>>(d_in[0], pwf, xn, flag);
  // 2. fused qkv+gate GEMM with qk-norm / sigmoid epilogue (N=3200 incl. pad tile)
  gemm_qkv_fused<<<dim3(25, 32), 256, 0, stream>>>(xn, Wcat, qkv2, gate, qnf, knf);
  // 3. V transpose
  vt_kernel<<<dim3(32, 32), 256, 0, stream>>>(qkv2, Vt);
  // 4. flash attention (32x32 MFMA, in-register softmax, depth-2 counted-vmcnt pipeline)
  flash_kernel<<<dim3(16, 32), 256, 0, stream>>>(qkv2, Vt, gate, ao);
  // 5. out = ao @ o_w^T + x (raw residual), dtype-dispatched store
  gemm_tiled<<<dim3(8, 32), 256, 0, stream>>>(ao, ow, d_out, d_in[0], flag,
                                              1024, 1024, 1024, 1024);
}